// Round 13
// baseline (283.461 us; speedup 1.0000x reference)
//
#include <hip/hip_runtime.h>
#include <hip/hip_bf16.h>
#include <math.h>

#define D_MODEL 1024
#define SEQ     2048
#define NHEAD   16

typedef __attribute__((ext_vector_type(8))) short bf16x8;
typedef __attribute__((ext_vector_type(8))) unsigned short u16x8;
typedef __attribute__((ext_vector_type(4))) float f32x4;
typedef const __attribute__((address_space(1))) unsigned int* gas_u32p;
typedef __attribute__((address_space(3))) unsigned int* las_u32p;

__device__ __forceinline__ void load16(const void* g, void* l) {
  __builtin_amdgcn_global_load_lds((gas_u32p)g, (las_u32p)l, 16, 0, 0);
}

__device__ __forceinline__ unsigned short f2bf(float f) {
  __hip_bfloat16 h = __float2bfloat16(f);
  return *(unsigned short*)&h;
}
__device__ __forceinline__ float bf2f(unsigned short u) {
  return __uint_as_float((unsigned)u << 16);
}
// nontemporal 16B store: builtin requires clang ext_vector, not HIP float4
__device__ __forceinline__ void nt_store_f4(f32x4 v, float* p) {
  __builtin_nontemporal_store(v, (f32x4*)p);
}

// ---------------------------------------------------------------------------
// fp32 -> bf16 for q,k,v in one launch (blockIdx.y selects tensor)
// ---------------------------------------------------------------------------
__global__ __launch_bounds__(256) void cvt3_bf16(
    const float4* __restrict__ q, const float4* __restrict__ k,
    const float4* __restrict__ v, ushort4* __restrict__ qo,
    ushort4* __restrict__ ko, ushort4* __restrict__ vo) {
  const int i = blockIdx.x * 256 + threadIdx.x;
  const float4* in = (blockIdx.y == 0) ? q : (blockIdx.y == 1) ? k : v;
  ushort4* out = (blockIdx.y == 0) ? qo : (blockIdx.y == 1) ? ko : vo;
  const float4 f = in[i];
  ushort4 u;
  u.x = f2bf(f.x); u.y = f2bf(f.y); u.z = f2bf(f.z); u.w = f2bf(f.w);
  out[i] = u;
}

// ---------------------------------------------------------------------------
// 4 x (W [1024 k][1024 n] fp32 -> Wt bf16 [n][k]), blockIdx.z selects
// ---------------------------------------------------------------------------
__global__ __launch_bounds__(256) void wt_cvt4(
    const float* __restrict__ W0, const float* __restrict__ W1,
    const float* __restrict__ W2, const float* __restrict__ W3,
    unsigned short* __restrict__ O0, unsigned short* __restrict__ O1,
    unsigned short* __restrict__ O2, unsigned short* __restrict__ O3) {
  __shared__ float t[64][65];
  const int z = blockIdx.z;
  const float* W = (z == 0) ? W0 : (z == 1) ? W1 : (z == 2) ? W2 : W3;
  unsigned short* Wh = (z == 0) ? O0 : (z == 1) ? O1 : (z == 2) ? O2 : O3;
  const int tid = threadIdx.x;
  const int k0 = blockIdx.y * 64, n0 = blockIdx.x * 64;
  #pragma unroll
  for (int it = 0; it < 4; ++it) {
    const int r = it * 16 + (tid >> 4), c4 = (tid & 15) * 4;
    const float4 f = *(const float4*)&W[(size_t)(k0 + r) * D_MODEL + n0 + c4];
    t[r][c4 + 0] = f.x; t[r][c4 + 1] = f.y;
    t[r][c4 + 2] = f.z; t[r][c4 + 3] = f.w;
  }
  __syncthreads();
  #pragma unroll
  for (int it = 0; it < 4; ++it) {
    const int n = it * 16 + (tid >> 4), k4 = (tid & 15) * 4;
    ushort4 uh;
    uh.x = f2bf(t[k4 + 0][n]); uh.y = f2bf(t[k4 + 1][n]);
    uh.z = f2bf(t[k4 + 2][n]); uh.w = f2bf(t[k4 + 3][n]);
    *(ushort4*)&Wh[(size_t)(n0 + n) * D_MODEL + k0 + k4] = uh;
  }
}

// ---------------------------------------------------------------------------
// Fused Q/K/V projections. 128x128 tile, BK=64, grid 768 (validated r7-r11).
// Q pre-scaled by 0.125*log2(e).
// ---------------------------------------------------------------------------
__global__ __launch_bounds__(512, 4) void gemm_qkv(
    const unsigned short* __restrict__ qx, const unsigned short* __restrict__ kx,
    const unsigned short* __restrict__ vx,
    const unsigned short* __restrict__ Wqt, const unsigned short* __restrict__ Wkt,
    const unsigned short* __restrict__ Wvt,
    const float* __restrict__ bq, const float* __restrict__ bk,
    const float* __restrict__ bv,
    unsigned short* __restrict__ Qo, unsigned short* __restrict__ Ko,
    unsigned short* __restrict__ Vto) {
  __shared__ char lds[65536];
  const int tid = threadIdx.x;
  const int lane = tid & 63, wid = tid >> 6;
  const int r16 = lane & 15, g = lane >> 4;
  const int bid = blockIdx.x;
  const int orig = (bid & 7) * 96 + (bid >> 3);
  const int which = orig >> 8;
  const int sub = orig & 255;
  const int bm = sub >> 3, bn = sub & 7;
  const int row0 = bm * 128, col0 = bn * 128;
  const int wm = wid >> 2, wn = wid & 3;

  const unsigned short* A = (which == 0) ? qx : (which == 1) ? kx : vx;
  const unsigned short* W = (which == 0) ? Wqt : (which == 1) ? Wkt : Wvt;
  const float* bias = (which == 0) ? bq : (which == 1) ? bk : bv;

  const unsigned short* Ag = A + (size_t)row0 * D_MODEL;
  const unsigned short* Bg = W + (size_t)col0 * D_MODEL;

  auto stage = [&](int buf, int k0) {
    char* base = lds + buf * 32768;
    #pragma unroll
    for (int c = 0; c < 2; ++c) {
      const int idx = c * 512 + tid;
      const int r = idx >> 3, ch = idx & 7;
      const size_t off = (size_t)r * D_MODEL + k0 + ((ch ^ (r & 7)) << 3);
      load16(Ag + off, base + idx * 16);
      load16(Bg + off, base + 16384 + idx * 16);
    }
  };

  stage(0, 0);
  f32x4 acc[4][2] = {};

  for (int s = 0; s < 16; ++s) {
    __syncthreads();
    if (s < 15) stage((s + 1) & 1, (s + 1) * 64);
    const char* base = lds + (s & 1) * 32768;
    #pragma unroll
    for (int kk = 0; kk < 2; ++kk) {
      bf16x8 a[4], b[2];
      #pragma unroll
      for (int mi = 0; mi < 4; ++mi) {
        const int r = wm * 64 + mi * 16 + r16;
        a[mi] = *(const bf16x8*)(base + r * 128 + (((g + kk * 4) ^ (r & 7)) << 4));
      }
      #pragma unroll
      for (int ni = 0; ni < 2; ++ni) {
        const int r = wn * 32 + ni * 16 + r16;
        b[ni] = *(const bf16x8*)(base + 16384 + r * 128 +
                                 (((g + kk * 4) ^ (r & 7)) << 4));
      }
      #pragma unroll
      for (int mi = 0; mi < 4; ++mi)
        #pragma unroll
        for (int ni = 0; ni < 2; ++ni)
          acc[mi][ni] = __builtin_amdgcn_mfma_f32_16x16x32_bf16(
              a[mi], b[ni], acc[mi][ni], 0, 0, 0);
    }
  }

  if (which < 2) {
    unsigned short* C = (which == 0) ? Qo : Ko;
    const float scale = (which == 0) ? 0.1803368802f : 1.0f;
    #pragma unroll
    for (int mi = 0; mi < 4; ++mi)
      #pragma unroll
      for (int ni = 0; ni < 2; ++ni) {
        const int col = col0 + wn * 32 + ni * 16 + r16;
        const float bb = bias[col];
        const int rowb = row0 + wm * 64 + mi * 16 + g * 4;
        #pragma unroll
        for (int j = 0; j < 4; ++j)
          C[(size_t)(rowb + j) * D_MODEL + col] =
              f2bf((acc[mi][ni][j] + bb) * scale);
      }
  } else {
    #pragma unroll
    for (int mi = 0; mi < 4; ++mi)
      #pragma unroll
      for (int ni = 0; ni < 2; ++ni) {
        const int col = col0 + wn * 32 + ni * 16 + r16;
        const int hh = col >> 6, dd = col & 63;
        const float bb = bias[col];
        const int rowb = row0 + wm * 64 + mi * 16 + g * 4;
        const int b_ = rowb >> 11, tt = rowb & 2047;
        ushort4 u;
        u.x = f2bf(acc[mi][ni][0] + bb);
        u.y = f2bf(acc[mi][ni][1] + bb);
        u.z = f2bf(acc[mi][ni][2] + bb);
        u.w = f2bf(acc[mi][ni][3] + bb);
        *(ushort4*)&Vto[((size_t)((b_ * NHEAD + hh) * 64 + dd)) * SEQ + tt] = u;
      }
  }
}

// ---------------------------------------------------------------------------
// Final GEMM: out = Oh @ Wh + bias, fp32. 64x128 tile, BK=64, grid 512.
// Output stored nontemporal (streaming, never re-read).
// ---------------------------------------------------------------------------
__global__ __launch_bounds__(512, 4) void gemm_fin64(
    const unsigned short* __restrict__ A, const unsigned short* __restrict__ B,
    const float* __restrict__ bias, float* __restrict__ O) {
  __shared__ char lds[49152];                 // 2 x (8K A + 16K B)
  const int tid = threadIdx.x;
  const int lane = tid & 63, wid = tid >> 6;
  const int r16 = lane & 15, g = lane >> 4;
  const int bid = blockIdx.x;
  const int orig = (bid & 7) * 64 + (bid >> 3);   // XCD swizzle (512%8==0)
  const int bm = orig >> 3, bn = orig & 7;
  const int row0 = bm * 64, col0 = bn * 128;
  const int wm = wid >> 2, wn = wid & 3;          // 2(m) x 4(n)

  const unsigned short* Ag = A + (size_t)row0 * D_MODEL;
  const unsigned short* Bg = B + (size_t)col0 * D_MODEL;

  auto stage = [&](int buf, int k0) {
    char* base = lds + buf * 24576;
    {                                          // A: 64 rows x 64 k
      const int r = tid >> 3, ch = tid & 7;
      load16(Ag + (size_t)r * D_MODEL + k0 + ((ch ^ (r & 7)) << 3),
             base + tid * 16);
    }
    #pragma unroll
    for (int c = 0; c < 2; ++c) {              // B: 128 rows x 64 k
      const int idx = c * 512 + tid;
      const int r = idx >> 3, ch = idx & 7;
      load16(Bg + (size_t)r * D_MODEL + k0 + ((ch ^ (r & 7)) << 3),
             base + 8192 + idx * 16);
    }
  };

  stage(0, 0);
  f32x4 acc[2][2] = {};

  for (int s = 0; s < 16; ++s) {
    __syncthreads();
    if (s < 15) stage((s + 1) & 1, (s + 1) * 64);
    const char* base = lds + (s & 1) * 24576;
    #pragma unroll
    for (int kk = 0; kk < 2; ++kk) {
      bf16x8 a[2], b[2];
      #pragma unroll
      for (int mi = 0; mi < 2; ++mi) {
        const int r = wm * 32 + mi * 16 + r16;
        a[mi] = *(const bf16x8*)(base + r * 128 + (((g + kk * 4) ^ (r & 7)) << 4));
      }
      #pragma unroll
      for (int ni = 0; ni < 2; ++ni) {
        const int r = wn * 32 + ni * 16 + r16;
        b[ni] = *(const bf16x8*)(base + 8192 + r * 128 +
                                 (((g + kk * 4) ^ (r & 7)) << 4));
      }
      #pragma unroll
      for (int mi = 0; mi < 2; ++mi)
        #pragma unroll
        for (int ni = 0; ni < 2; ++ni)
          acc[mi][ni] = __builtin_amdgcn_mfma_f32_16x16x32_bf16(
              a[mi], b[ni], acc[mi][ni], 0, 0, 0);
    }
  }

  #pragma unroll
  for (int mi = 0; mi < 2; ++mi)
    #pragma unroll
    for (int ni = 0; ni < 2; ++ni) {
      const int col = col0 + wn * 32 + ni * 16 + r16;
      const float bb = bias[col];
      const int rowb = row0 + wm * 32 + mi * 16 + g * 4;
      #pragma unroll
      for (int j = 0; j < 4; ++j)
        __builtin_nontemporal_store(
            acc[mi][ni][j] + bb,
            &O[(size_t)(rowb + j) * D_MODEL + col]);
    }
}

// ---------------------------------------------------------------------------
// Two-pass MFMA attention, QB=64 — round-9/11 validated sync structure.
// ONLY change: attn + Oh stores are NONTEMPORAL (537 MB streaming write no
// longer evicts K/V working set from per-XCD L2).
// ---------------------------------------------------------------------------
__global__ __launch_bounds__(512, 4) void attn_2pass(
    const unsigned short* __restrict__ Qb,   // bf16, pre-scaled 0.125*log2e
    const unsigned short* __restrict__ Kb,   // bf16 [4096][1024]
    const unsigned short* __restrict__ Vt,   // bf16 [32*64][2048]
    const int* __restrict__ mask,            // [2][2048]
    float* __restrict__ attn,                // [32][2048][2048]
    unsigned short* __restrict__ Oh) {       // bf16 [4096][1024]
  __shared__ char lds[74752];
  char* const Kbuf = lds;                    // 4 x 8192
  char* const Vbuf = lds + 32768;            // 4 x 8192 (slot0 = Q staging)
  char* const Pt   = lds + 65536;            // 8192: P tile 64x64 bf16
  float* const red = (float*)(lds + 73728);  // [4 wt][64 q]

  const int tid  = threadIdx.x;
  const int lane = tid & 63;
  const int wid  = tid >> 6;
  const int r16  = lane & 15;
  const int g    = lane >> 4;
  const int wq2  = wid >> 2;
  const int wt   = wid & 3;

  const int bid  = blockIdx.x;
  const int orig = (bid & 7) * 128 + (bid >> 3);   // XCD swizzle (1024%8==0)
  const int bh   = orig >> 5;
  const int qblk = orig & 31;
  const int b    = bh >> 4, h = bh & 15;
  const int q0   = qblk * 64;

  const unsigned short* Kg0 = Kb + (size_t)(b * SEQ) * D_MODEL + h * 64;
  const unsigned short* Qg0 = Qb + (size_t)(b * SEQ + q0) * D_MODEL + h * 64;
  const unsigned short* Vg0 = Vt + (size_t)(bh * 64) * SEQ;
  const int* mrow = mask + b * SEQ;

  const int srow = tid >> 3, sch = tid & 7;
  const int ssw  = srow & 7;

  auto stageK = [&](int t) {
    load16((const char*)(Kg0 + (size_t)(t * 64 + srow) * D_MODEL) +
               ((sch ^ ssw) << 4),
           Kbuf + ((t & 3) << 13) + tid * 16);
  };
  auto stageV = [&](int t) {
    load16((const char*)(Vg0 + (size_t)srow * SEQ + t * 64) +
               ((sch ^ ssw) << 4),
           Vbuf + ((t & 3) << 13) + tid * 16);
  };

  // per-lane mask bits for t = i*64 + wt*16 + r16 (consumed before staging)
  const int tb = wt * 16 + r16;
  unsigned mbits = 0;
  #pragma unroll 4
  for (int i = 0; i < 32; ++i)
    mbits |= (mrow[i * 64 + tb] ? 1u : 0u) << i;
  asm volatile("s_waitcnt vmcnt(0)" ::: "memory");  // clean FIFO before staging

  // ---- prologue: Q into Vbuf slot0, K tiles 0..2 -------------------------
  load16((const char*)(Qg0 + (size_t)srow * D_MODEL) + ((sch ^ ssw) << 4),
         Vbuf + tid * 16);
  stageK(0); stageK(1); stageK(2);
  asm volatile("s_waitcnt vmcnt(3)\n\ts_barrier" ::: "memory");  // Q resident

  bf16x8 qa[2][2];
  #pragma unroll
  for (int f = 0; f < 2; ++f) {
    const int row = wq2 * 32 + f * 16 + r16;
    const int sw = (row & 7) << 4;
    qa[f][0] = *(const bf16x8*)(Vbuf + row * 128 + ((g * 16) ^ sw));
    qa[f][1] = *(const bf16x8*)(Vbuf + row * 128 + ((g * 16 + 64) ^ sw));
  }

  const int krow = wt * 16 + r16;
  const int ksw  = (krow & 7) << 4;

  // ---- pass 1: rowsums ---------------------------------------------------
  float rs[2][4] = {};
  for (int i = 0; i < 32; ++i) {
    if (i < 30)
      asm volatile("s_waitcnt vmcnt(2)\n\ts_barrier" ::: "memory");
    else if (i == 30)
      asm volatile("s_waitcnt vmcnt(1)\n\ts_barrier" ::: "memory");
    else
      asm volatile("s_waitcnt vmcnt(0)\n\ts_barrier" ::: "memory");
    if (i + 3 < 32) stageK(i + 3);
    const char* Kt = Kbuf + ((i & 3) << 13);
    const bf16x8 kb0 = *(const bf16x8*)(Kt + krow * 128 + ((g * 16) ^ ksw));
    const bf16x8 kb1 = *(const bf16x8*)(Kt + krow * 128 + ((g * 16 + 64) ^ ksw));
    f32x4 c0 = {0.f, 0.f, 0.f, 0.f}, c1 = {0.f, 0.f, 0.f, 0.f};
    __builtin_amdgcn_s_setprio(1);
    c0 = __builtin_amdgcn_mfma_f32_16x16x32_bf16(qa[0][0], kb0, c0, 0, 0, 0);
    c0 = __builtin_amdgcn_mfma_f32_16x16x32_bf16(qa[0][1], kb1, c0, 0, 0, 0);
    c1 = __builtin_amdgcn_mfma_f32_16x16x32_bf16(qa[1][0], kb0, c1, 0, 0, 0);
    c1 = __builtin_amdgcn_mfma_f32_16x16x32_bf16(qa[1][1], kb1, c1, 0, 0, 0);
    __builtin_amdgcn_s_setprio(0);
    if (!((mbits >> i) & 1u)) {
      rs[0][0] += exp2f(c0[0]); rs[0][1] += exp2f(c0[1]);
      rs[0][2] += exp2f(c0[2]); rs[0][3] += exp2f(c0[3]);
      rs[1][0] += exp2f(c1[0]); rs[1][1] += exp2f(c1[1]);
      rs[1][2] += exp2f(c1[2]); rs[1][3] += exp2f(c1[3]);
    }
  }

  // ---- rowsum reduction (16-lane groups share a q-frag row set) ----------
  #pragma unroll
  for (int f = 0; f < 2; ++f)
    #pragma unroll
    for (int j = 0; j < 4; ++j) {
      float v = rs[f][j];
      v += __shfl_xor(v, 1); v += __shfl_xor(v, 2);
      v += __shfl_xor(v, 4); v += __shfl_xor(v, 8);
      rs[f][j] = v;
    }
  if (r16 == 0) {
    #pragma unroll
    for (int f = 0; f < 2; ++f)
      #pragma unroll
      for (int j = 0; j < 4; ++j)
        red[wt * 64 + wq2 * 32 + f * 16 + g * 4 + j] = rs[f][j];
  }
  __syncthreads();

  float inv_[2][4];
  #pragma unroll
  for (int f = 0; f < 2; ++f)
    #pragma unroll
    for (int j = 0; j < 4; ++j) {
      const int row = wq2 * 32 + f * 16 + g * 4 + j;
      inv_[f][j] = 1.f / (red[0 * 64 + row] + red[1 * 64 + row] +
                          red[2 * 64 + row] + red[3 * 64 + row]);
    }

  // ---- pass 2 prologue ---------------------------------------------------
  stageK(0); stageV(0); stageK(1); stageV(1); stageK(2); stageV(2);

  f32x4 o0 = {0.f, 0.f, 0.f, 0.f}, o1 = {0.f, 0.f, 0.f, 0.f};
  // readback mapping: thread -> q row tid>>3, 8 cols at (tid&7)*8
  const int rbq = tid >> 3, rbc8 = (tid & 7) * 8;
  const int rboff = (rbq * 128 + rbc8 * 2) ^ ((rbq & 7) << 4);
  float* const aT = attn + ((size_t)bh * SEQ + q0 + rbq) * SEQ + rbc8;

  for (int i = 0; i < 32; ++i) {
    // FIFO (2 loads + 2 stores/iter, 3-deep prefetch): 4,6,8,10..10,8,6
    if (i >= 3 && i <= 29)
      asm volatile("s_waitcnt vmcnt(10)\n\ts_barrier" ::: "memory");
    else if (i == 2 || i == 30)
      asm volatile("s_waitcnt vmcnt(8)\n\ts_barrier" ::: "memory");
    else if (i == 1 || i == 31)
      asm volatile("s_waitcnt vmcnt(6)\n\ts_barrier" ::: "memory");
    else
      asm volatile("s_waitcnt vmcnt(4)\n\ts_barrier" ::: "memory");
    if (i + 3 < 32) { stageK(i + 3); stageV(i + 3); }

    const char* Kt = Kbuf + ((i & 3) << 13);
    const bf16x8 kb0 = *(const bf16x8*)(Kt + krow * 128 + ((g * 16) ^ ksw));
    const bf16x8 kb1 = *(const bf16x8*)(Kt + krow * 128 + ((g * 16 + 64) ^ ksw));
    f32x4 c0 = {0.f, 0.f, 0.f, 0.f}, c1 = {0.f, 0.f, 0.f, 0.f};
    __builtin_amdgcn_s_setprio(1);
    c0 = __builtin_amdgcn_mfma_f32_16x16x32_bf16(qa[0][0], kb0, c0, 0, 0, 0);
    c0 = __builtin_amdgcn_mfma_f32_16x16x32_bf16(qa[0][1], kb1, c0, 0, 0, 0);
    c1 = __builtin_amdgcn_mfma_f32_16x16x32_bf16(qa[1][0], kb0, c1, 0, 0, 0);
    c1 = __builtin_amdgcn_mfma_f32_16x16x32_bf16(qa[1][1], kb1, c1, 0, 0, 0);
    __builtin_amdgcn_s_setprio(0);

    const unsigned mk = (mbits >> i) & 1u;
    float p[2][4];
    p[0][0] = mk ? 0.f : exp2f(c0[0]) * inv_[0][0];
    p[0][1] = mk ? 0.f : exp2f(c0[1]) * inv_[0][1];
    p[0][2] = mk ? 0.f : exp2f(c0[2]) * inv_[0][2];
    p[0][3] = mk ? 0.f : exp2f(c0[3]) * inv_[0][3];
    p[1][0] = mk ? 0.f : exp2f(c1[0]) * inv_[1][0];
    p[1][1] = mk ? 0.f : exp2f(c1[1]) * inv_[1][1];
    p[1][2] = mk ? 0.f : exp2f(c1[2]) * inv_[1][2];
    p[1][3] = mk ? 0.f : exp2f(c1[3]) * inv_[1][3];

    #pragma unroll
    for (int f = 0; f < 2; ++f)
      #pragma unroll
      for (int j = 0; j < 4; ++j) {
        const int row = wq2 * 32 + f * 16 + g * 4 + j;
        *(unsigned short*)(Pt + ((row * 128 + tb * 2) ^ ((row & 7) << 4))) =
            f2bf(p[f][j]);
      }

    asm volatile("s_waitcnt lgkmcnt(0)\n\ts_barrier" ::: "memory");

    const char* Vtl = Vbuf + ((i & 3) << 13);
    const bf16x8 vb0 = *(const bf16x8*)(Vtl + krow * 128 + ((g * 16) ^ ksw));
    const bf16x8 vb1 = *(const bf16x8*)(Vtl + krow * 128 + ((g * 16 + 64) ^ ksw));
    {
      const int pr0 = wq2 * 32 + r16;
      const int psw0 = (pr0 & 7) << 4;
      const bf16x8 pa0 = *(const bf16x8*)(Pt + pr0 * 128 + ((g * 16) ^ psw0));
      const bf16x8 pa1 = *(const bf16x8*)(Pt + pr0 * 128 + ((g * 16 + 64) ^ psw0));
      const int pr1 = pr0 + 16;
      const int psw1 = (pr1 & 7) << 4;
      const bf16x8 pb0 = *(const bf16x8*)(Pt + pr1 * 128 + ((g * 16) ^ psw1));
      const bf16x8 pb1 = *(const bf16x8*)(Pt + pr1 * 128 + ((g * 16 + 64) ^ psw1));
      __builtin_amdgcn_s_setprio(1);
      o0 = __builtin_amdgcn_mfma_f32_16x16x32_bf16(pa0, vb0, o0, 0, 0, 0);
      o0 = __builtin_amdgcn_mfma_f32_16x16x32_bf16(pa1, vb1, o0, 0, 0, 0);
      o1 = __builtin_amdgcn_mfma_f32_16x16x32_bf16(pb0, vb0, o1, 0, 0, 0);
      o1 = __builtin_amdgcn_mfma_f32_16x16x32_bf16(pb1, vb1, o1, 0, 0, 0);
      __builtin_amdgcn_s_setprio(0);
    }

    // coalesced attn write: u16x8 LDS readback -> 2 NONTEMPORAL f32x4 stores
    {
      const u16x8 pv = *(const u16x8*)(Pt + rboff);
      f32x4 oA, oB;
      oA[0] = bf2f(pv[0]); oA[1] = bf2f(pv[1]);
      oA[2] = bf2f(pv[2]); oA[3] = bf2f(pv[3]);
      oB[0] = bf2f(pv[4]); oB[1] = bf2f(pv[5]);
      oB[2] = bf2f(pv[6]); oB[3] = bf2f(pv[7]);
      nt_store_f4(oA, aT + (size_t)i * 64);
      nt_store_f4(oB, aT + (size_t)i * 64 + 4);
    }
  }

  // ---- O epilogue (normalized), bf16, nontemporal ------------------------
  #pragma unroll
  for (int f = 0; f < 2; ++f)
    #pragma unroll
    for (int j = 0; j < 4; ++j) {
      const int row = q0 + wq2 * 32 + f * 16 + g * 4 + j;
      const size_t idx = (size_t)(b * SEQ + row) * D_MODEL + h * 64 + wt * 16 + r16;
      __builtin_nontemporal_store(f2bf(f ? o1[j] : o0[j]), &Oh[idx]);
    }
}

// ---------------------------------------------------------------------------
extern "C" void kernel_launch(void* const* d_in, const int* in_sizes, int n_in,
                              void* d_out, int out_size, void* d_ws, size_t ws_size,
                              hipStream_t stream) {
  const float* v    = (const float*)d_in[0];
  const float* k    = (const float*)d_in[1];
  const float* q    = (const float*)d_in[2];
  const int*   mask = (const int*)  d_in[3];
  const float* Wq   = (const float*)d_in[4];
  const float* bq   = (const float*)d_in[5];
  const float* Wk   = (const float*)d_in[6];
  const float* bk   = (const float*)d_in[7];
  const float* Wv   = (const float*)d_in[8];
  const float* bv   = (const float*)d_in[9];
  const float* Wo   = (const float*)d_in[10];
  const float* bo   = (const float*)d_in[11];

  const size_t NTOK = (size_t)2 * SEQ;            // 4096 tokens
  const size_t TOKF = NTOK * D_MODEL;             // 4,194,304 elements
  const size_t WSZ  = (size_t)D_MODEL * D_MODEL;  // 1,048,576
  float* out  = (float*)d_out;
  float* attn = out + TOKF;

  unsigned short* qx   = (unsigned short*)d_ws;   // bf16 inputs
  unsigned short* kx   = qx + TOKF;
  unsigned short* vx   = kx + TOKF;
  unsigned short* Qbf  = vx + TOKF;               // projections
  unsigned short* Kbf  = Qbf + TOKF;
  unsigned short* Vtb  = Kbf + TOKF;
  unsigned short* Ohb  = Vtb + TOKF;              // attn O (bf16)
  unsigned short* Wqt  = Ohb + TOKF;              // transposed bf16 weights
  unsigned short* Wkt  = Wqt + WSZ;
  unsigned short* Wvt  = Wkt + WSZ;
  unsigned short* Woth = Wvt + WSZ;

  const int cvtg = (int)(TOKF / 4 / 256);         // 4096 blocks
  cvt3_bf16<<<dim3(cvtg, 3), 256, 0, stream>>>(
      (const float4*)q, (const float4*)k, (const float4*)v,
      (ushort4*)qx, (ushort4*)kx, (ushort4*)vx);
  wt_cvt4<<<dim3(16, 16, 4), 256, 0, stream>>>(Wq, Wk, Wv, Wo,
                                               Wqt, Wkt, Wvt, Woth);

  gemm_qkv<<<768, 512, 0, stream>>>(qx, kx, vx, Wqt, Wkt, Wvt,
                                    bq, bk, bv, Qbf, Kbf, Vtb);

  attn_2pass<<<1024, 512, 0, stream>>>(Qbf, Kbf, Vtb, mask, attn, Ohb);

  gemm_fin64<<<512, 512, 0, stream>>>(Ohb, Woth, bo, out);
}

// Round 14
// 243.498 us; speedup vs baseline: 1.1641x; 1.1641x over previous
//
#include <hip/hip_runtime.h>
#include <hip/hip_bf16.h>
#include <math.h>

#define D_MODEL 1024
#define SEQ     2048
#define NHEAD   16

typedef __attribute__((ext_vector_type(8))) short bf16x8;
typedef __attribute__((ext_vector_type(4))) float f32x4;
typedef const __attribute__((address_space(1))) unsigned int* gas_u32p;
typedef __attribute__((address_space(3))) unsigned int* las_u32p;

__device__ __forceinline__ void load16(const void* g, void* l) {
  __builtin_amdgcn_global_load_lds((gas_u32p)g, (las_u32p)l, 16, 0, 0);
}

__device__ __forceinline__ unsigned short f2bf(float f) {
  __hip_bfloat16 h = __float2bfloat16(f);
  return *(unsigned short*)&h;
}
__device__ __forceinline__ float bf2f(unsigned short u) {
  return __uint_as_float((unsigned)u << 16);
}
__device__ __forceinline__ void nt_store_f4(f32x4 v, float* p) {
  __builtin_nontemporal_store(v, (f32x4*)p);
}

// ---------------------------------------------------------------------------
// fp32 -> bf16 for q,k,v in one launch (blockIdx.y selects tensor)
// ---------------------------------------------------------------------------
__global__ __launch_bounds__(256) void cvt3_bf16(
    const float4* __restrict__ q, const float4* __restrict__ k,
    const float4* __restrict__ v, ushort4* __restrict__ qo,
    ushort4* __restrict__ ko, ushort4* __restrict__ vo) {
  const int i = blockIdx.x * 256 + threadIdx.x;
  const float4* in = (blockIdx.y == 0) ? q : (blockIdx.y == 1) ? k : v;
  ushort4* out = (blockIdx.y == 0) ? qo : (blockIdx.y == 1) ? ko : vo;
  const float4 f = in[i];
  ushort4 u;
  u.x = f2bf(f.x); u.y = f2bf(f.y); u.z = f2bf(f.z); u.w = f2bf(f.w);
  out[i] = u;
}

// ---------------------------------------------------------------------------
// 4 x (W [1024 k][1024 n] fp32 -> Wt bf16 [n][k]), blockIdx.z selects
// ---------------------------------------------------------------------------
__global__ __launch_bounds__(256) void wt_cvt4(
    const float* __restrict__ W0, const float* __restrict__ W1,
    const float* __restrict__ W2, const float* __restrict__ W3,
    unsigned short* __restrict__ O0, unsigned short* __restrict__ O1,
    unsigned short* __restrict__ O2, unsigned short* __restrict__ O3) {
  __shared__ float t[64][65];
  const int z = blockIdx.z;
  const float* W = (z == 0) ? W0 : (z == 1) ? W1 : (z == 2) ? W2 : W3;
  unsigned short* Wh = (z == 0) ? O0 : (z == 1) ? O1 : (z == 2) ? O2 : O3;
  const int tid = threadIdx.x;
  const int k0 = blockIdx.y * 64, n0 = blockIdx.x * 64;
  #pragma unroll
  for (int it = 0; it < 4; ++it) {
    const int r = it * 16 + (tid >> 4), c4 = (tid & 15) * 4;
    const float4 f = *(const float4*)&W[(size_t)(k0 + r) * D_MODEL + n0 + c4];
    t[r][c4 + 0] = f.x; t[r][c4 + 1] = f.y;
    t[r][c4 + 2] = f.z; t[r][c4 + 3] = f.w;
  }
  __syncthreads();
  #pragma unroll
  for (int it = 0; it < 4; ++it) {
    const int n = it * 16 + (tid >> 4), k4 = (tid & 15) * 4;
    ushort4 uh;
    uh.x = f2bf(t[k4 + 0][n]); uh.y = f2bf(t[k4 + 1][n]);
    uh.z = f2bf(t[k4 + 2][n]); uh.w = f2bf(t[k4 + 3][n]);
    *(ushort4*)&Wh[(size_t)(n0 + n) * D_MODEL + k0 + k4] = uh;
  }
}

// ---------------------------------------------------------------------------
// Fused Q/K/V projections. 128x128 tile, BK=64, grid 768 (validated r7-r13).
// Q pre-scaled by 0.125*log2(e).
// ---------------------------------------------------------------------------
__global__ __launch_bounds__(512, 4) void gemm_qkv(
    const unsigned short* __restrict__ qx, const unsigned short* __restrict__ kx,
    const unsigned short* __restrict__ vx,
    const unsigned short* __restrict__ Wqt, const unsigned short* __restrict__ Wkt,
    const unsigned short* __restrict__ Wvt,
    const float* __restrict__ bq, const float* __restrict__ bk,
    const float* __restrict__ bv,
    unsigned short* __restrict__ Qo, unsigned short* __restrict__ Ko,
    unsigned short* __restrict__ Vto) {
  __shared__ char lds[65536];
  const int tid = threadIdx.x;
  const int lane = tid & 63, wid = tid >> 6;
  const int r16 = lane & 15, g = lane >> 4;
  const int bid = blockIdx.x;
  const int orig = (bid & 7) * 96 + (bid >> 3);
  const int which = orig >> 8;
  const int sub = orig & 255;
  const int bm = sub >> 3, bn = sub & 7;
  const int row0 = bm * 128, col0 = bn * 128;
  const int wm = wid >> 2, wn = wid & 3;

  const unsigned short* A = (which == 0) ? qx : (which == 1) ? kx : vx;
  const unsigned short* W = (which == 0) ? Wqt : (which == 1) ? Wkt : Wvt;
  const float* bias = (which == 0) ? bq : (which == 1) ? bk : bv;

  const unsigned short* Ag = A + (size_t)row0 * D_MODEL;
  const unsigned short* Bg = W + (size_t)col0 * D_MODEL;

  auto stage = [&](int buf, int k0) {
    char* base = lds + buf * 32768;
    #pragma unroll
    for (int c = 0; c < 2; ++c) {
      const int idx = c * 512 + tid;
      const int r = idx >> 3, ch = idx & 7;
      const size_t off = (size_t)r * D_MODEL + k0 + ((ch ^ (r & 7)) << 3);
      load16(Ag + off, base + idx * 16);
      load16(Bg + off, base + 16384 + idx * 16);
    }
  };

  stage(0, 0);
  f32x4 acc[4][2] = {};

  for (int s = 0; s < 16; ++s) {
    __syncthreads();
    if (s < 15) stage((s + 1) & 1, (s + 1) * 64);
    const char* base = lds + (s & 1) * 32768;
    #pragma unroll
    for (int kk = 0; kk < 2; ++kk) {
      bf16x8 a[4], b[2];
      #pragma unroll
      for (int mi = 0; mi < 4; ++mi) {
        const int r = wm * 64 + mi * 16 + r16;
        a[mi] = *(const bf16x8*)(base + r * 128 + (((g + kk * 4) ^ (r & 7)) << 4));
      }
      #pragma unroll
      for (int ni = 0; ni < 2; ++ni) {
        const int r = wn * 32 + ni * 16 + r16;
        b[ni] = *(const bf16x8*)(base + 16384 + r * 128 +
                                 (((g + kk * 4) ^ (r & 7)) << 4));
      }
      #pragma unroll
      for (int mi = 0; mi < 4; ++mi)
        #pragma unroll
        for (int ni = 0; ni < 2; ++ni)
          acc[mi][ni] = __builtin_amdgcn_mfma_f32_16x16x32_bf16(
              a[mi], b[ni], acc[mi][ni], 0, 0, 0);
    }
  }

  if (which < 2) {
    unsigned short* C = (which == 0) ? Qo : Ko;
    const float scale = (which == 0) ? 0.1803368802f : 1.0f;
    #pragma unroll
    for (int mi = 0; mi < 4; ++mi)
      #pragma unroll
      for (int ni = 0; ni < 2; ++ni) {
        const int col = col0 + wn * 32 + ni * 16 + r16;
        const float bb = bias[col];
        const int rowb = row0 + wm * 64 + mi * 16 + g * 4;
        #pragma unroll
        for (int j = 0; j < 4; ++j)
          C[(size_t)(rowb + j) * D_MODEL + col] =
              f2bf((acc[mi][ni][j] + bb) * scale);
      }
  } else {
    #pragma unroll
    for (int mi = 0; mi < 4; ++mi)
      #pragma unroll
      for (int ni = 0; ni < 2; ++ni) {
        const int col = col0 + wn * 32 + ni * 16 + r16;
        const int hh = col >> 6, dd = col & 63;
        const float bb = bias[col];
        const int rowb = row0 + wm * 64 + mi * 16 + g * 4;
        const int b_ = rowb >> 11, tt = rowb & 2047;
        ushort4 u;
        u.x = f2bf(acc[mi][ni][0] + bb);
        u.y = f2bf(acc[mi][ni][1] + bb);
        u.z = f2bf(acc[mi][ni][2] + bb);
        u.w = f2bf(acc[mi][ni][3] + bb);
        *(ushort4*)&Vto[((size_t)((b_ * NHEAD + hh) * 64 + dd)) * SEQ + tt] = u;
      }
  }
}

// ---------------------------------------------------------------------------
// Final GEMM: out = Oh @ Wh + bias, fp32. 64x128 tile, BK=64, grid 512.
// (validated r10-r13)
// ---------------------------------------------------------------------------
__global__ __launch_bounds__(512, 4) void gemm_fin64(
    const unsigned short* __restrict__ A, const unsigned short* __restrict__ B,
    const float* __restrict__ bias, float* __restrict__ O) {
  __shared__ char lds[49152];
  const int tid = threadIdx.x;
  const int lane = tid & 63, wid = tid >> 6;
  const int r16 = lane & 15, g = lane >> 4;
  const int bid = blockIdx.x;
  const int orig = (bid & 7) * 64 + (bid >> 3);
  const int bm = orig >> 3, bn = orig & 7;
  const int row0 = bm * 64, col0 = bn * 128;
  const int wm = wid >> 2, wn = wid & 3;

  const unsigned short* Ag = A + (size_t)row0 * D_MODEL;
  const unsigned short* Bg = B + (size_t)col0 * D_MODEL;

  auto stage = [&](int buf, int k0) {
    char* base = lds + buf * 24576;
    {
      const int r = tid >> 3, ch = tid & 7;
      load16(Ag + (size_t)r * D_MODEL + k0 + ((ch ^ (r & 7)) << 3),
             base + tid * 16);
    }
    #pragma unroll
    for (int c = 0; c < 2; ++c) {
      const int idx = c * 512 + tid;
      const int r = idx >> 3, ch = idx & 7;
      load16(Bg + (size_t)r * D_MODEL + k0 + ((ch ^ (r & 7)) << 3),
             base + 8192 + idx * 16);
    }
  };

  stage(0, 0);
  f32x4 acc[2][2] = {};

  for (int s = 0; s < 16; ++s) {
    __syncthreads();
    if (s < 15) stage((s + 1) & 1, (s + 1) * 64);
    const char* base = lds + (s & 1) * 24576;
    #pragma unroll
    for (int kk = 0; kk < 2; ++kk) {
      bf16x8 a[2], b[2];
      #pragma unroll
      for (int mi = 0; mi < 2; ++mi) {
        const int r = wm * 32 + mi * 16 + r16;
        a[mi] = *(const bf16x8*)(base + r * 128 + (((g + kk * 4) ^ (r & 7)) << 4));
      }
      #pragma unroll
      for (int ni = 0; ni < 2; ++ni) {
        const int r = wn * 32 + ni * 16 + r16;
        b[ni] = *(const bf16x8*)(base + 8192 + r * 128 +
                                 (((g + kk * 4) ^ (r & 7)) << 4));
      }
      #pragma unroll
      for (int mi = 0; mi < 2; ++mi)
        #pragma unroll
        for (int ni = 0; ni < 2; ++ni)
          acc[mi][ni] = __builtin_amdgcn_mfma_f32_16x16x32_bf16(
              a[mi], b[ni], acc[mi][ni], 0, 0, 0);
    }
  }

  #pragma unroll
  for (int mi = 0; mi < 2; ++mi)
    #pragma unroll
    for (int ni = 0; ni < 2; ++ni) {
      const int col = col0 + wn * 32 + ni * 16 + r16;
      const float bb = bias[col];
      const int rowb = row0 + wm * 32 + mi * 16 + g * 4;
      #pragma unroll
      for (int j = 0; j < 4; ++j)
        __builtin_nontemporal_store(
            acc[mi][ni][j] + bb,
            &O[(size_t)(rowb + j) * D_MODEL + col]);
    }
}

// ---------------------------------------------------------------------------
// Two-pass MFMA attention, QB=64, 32-t tiles, ring-6 K/V, 52.5 KB LDS ->
// 3 blocks/CU (24 waves, +50% TLP vs r13). Waves: wq(0..3) x wt(0..1).
// Waves 0-3 stage K, 4-7 stage V (1 vm-load/wave/iter). Prefetch depth 5
// half-tiles (~2.5 iter slack > HBM latency). vmcnt ladders derived below.
// ---------------------------------------------------------------------------
__global__ __launch_bounds__(512, 6) void attn_2pass(
    const unsigned short* __restrict__ Qb,   // bf16, pre-scaled 0.125*log2e
    const unsigned short* __restrict__ Kb,   // bf16 [4096][1024]
    const unsigned short* __restrict__ Vt,   // bf16 [32*64][2048]
    const int* __restrict__ mask,            // [2][2048]
    float* __restrict__ attn,                // [32][2048][2048]
    unsigned short* __restrict__ Oh) {       // bf16 [4096][1024]
  __shared__ char lds[53760];
  char* const Kbuf = lds;                    // 6 x 4096: K tiles [32 t][128B]
  char* const Vbuf = lds + 24576;            // 6 x 4096: V tiles [64 d][64B]
  char* const Pt   = lds + 49152;            // 4096: P tile [64 q][64B]
  float* const red = (float*)(lds + 53248);  // [2 wt][64 q]

  const int tid  = threadIdx.x;
  const int lane = tid & 63;
  const int wid  = tid >> 6;
  const int r16  = lane & 15;
  const int g    = lane >> 4;
  const int wq   = wid >> 1;                 // q-quarter (16 rows)
  const int wt   = wid & 1;                  // t half (QK) / d half (PV)

  const int bid  = blockIdx.x;
  const int orig = (bid & 7) * 128 + (bid >> 3);   // XCD swizzle (1024%8==0)
  const int bh   = orig >> 5;
  const int qblk = orig & 31;
  const int b    = bh >> 4, h = bh & 15;
  const int q0   = qblk * 64;

  const unsigned short* Kg0 = Kb + (size_t)(b * SEQ) * D_MODEL + h * 64;
  const unsigned short* Qg0 = Qb + (size_t)(b * SEQ + q0) * D_MODEL + h * 64;
  const unsigned short* Vg0 = Vt + (size_t)(bh * 64) * SEQ;
  const int* mrow = mask + b * SEQ;

  // staging: waves 0-3 (tid<256) stage K tiles, waves 4-7 stage V tiles.
  const int t8 = tid & 255;
  const int ks_row = t8 >> 3, ks_ch = t8 & 7;      // K: 32 rows x 8 chunks
  const int vs_row = t8 >> 2, vs_ch = t8 & 3;      // V: 64 rows x 4 chunks
  auto stageK = [&](int t, int slot) {
    load16((const char*)(Kg0 + (size_t)(t * 32 + ks_row) * D_MODEL) +
               ((ks_ch ^ (ks_row & 7)) << 4),
           Kbuf + (slot << 12) + t8 * 16);
  };
  auto stageV = [&](int t, int slot) {
    load16((const char*)(Vg0 + (size_t)vs_row * SEQ + t * 32) +
               ((vs_ch ^ ((vs_row >> 2) & 3)) << 4),
           Vbuf + (slot << 12) + t8 * 16);
  };
  auto stageKV = [&](int t, int slot) {
    if (tid < 256) stageK(t, slot); else stageV(t, slot);
  };

  // per-lane mask bits for t = i*32 + wt*16 + r16, i in [0,64)
  const int tb = wt * 16 + r16;
  unsigned long long mbits = 0;
  #pragma unroll 8
  for (int i = 0; i < 64; ++i)
    mbits |= (unsigned long long)(mrow[i * 32 + tb] ? 1 : 0) << i;
  asm volatile("s_waitcnt vmcnt(0)" ::: "memory");

  // ---- pass 1 prologue: Q into Vbuf (8K), K tiles 0..4 -------------------
  load16((const char*)(Qg0 + (size_t)(tid >> 3) * D_MODEL) +
             (((tid & 7) ^ ((tid >> 3) & 7)) << 4),
         Vbuf + tid * 16);
  if (tid < 256) {
    stageK(0, 0); stageK(1, 1); stageK(2, 2); stageK(3, 3); stageK(4, 4);
  }
  asm volatile("s_waitcnt vmcnt(0)\n\ts_barrier" ::: "memory");

  bf16x8 qa0, qa1;
  {
    const int row = wq * 16 + r16;
    const int sw = (row & 7) << 4;
    qa0 = *(const bf16x8*)(Vbuf + row * 128 + ((g * 16) ^ sw));
    qa1 = *(const bf16x8*)(Vbuf + row * 128 + ((g * 16 + 64) ^ sw));
  }

  const int krow = wt * 16 + r16;            // t-row in K tile [0,32)
  const int ksw  = (krow & 7) << 4;

  // ---- pass 1: rowsums (64 iters). per-wave 1 load/iter (waves 0-3). -----
  // vmcnt ladder: i<=59 -> 4; 60/61/62/63 -> 3/2/1/0.
  float rs[4] = {};
  {
    int slot = 0, pslot = 5;
    for (int i = 0; i < 64; ++i) {
      if (i <= 59)
        asm volatile("s_waitcnt vmcnt(4)\n\ts_barrier" ::: "memory");
      else if (i == 60)
        asm volatile("s_waitcnt vmcnt(3)\n\ts_barrier" ::: "memory");
      else if (i == 61)
        asm volatile("s_waitcnt vmcnt(2)\n\ts_barrier" ::: "memory");
      else if (i == 62)
        asm volatile("s_waitcnt vmcnt(1)\n\ts_barrier" ::: "memory");
      else
        asm volatile("s_waitcnt vmcnt(0)\n\ts_barrier" ::: "memory");
      if (i + 5 < 64 && tid < 256) stageK(i + 5, pslot);
      const char* Kt = Kbuf + (slot << 12);
      const bf16x8 kb0 = *(const bf16x8*)(Kt + krow * 128 + ((g * 16) ^ ksw));
      const bf16x8 kb1 = *(const bf16x8*)(Kt + krow * 128 + ((g * 16 + 64) ^ ksw));
      f32x4 c = {0.f, 0.f, 0.f, 0.f};
      __builtin_amdgcn_s_setprio(1);
      c = __builtin_amdgcn_mfma_f32_16x16x32_bf16(qa0, kb0, c, 0, 0, 0);
      c = __builtin_amdgcn_mfma_f32_16x16x32_bf16(qa1, kb1, c, 0, 0, 0);
      __builtin_amdgcn_s_setprio(0);
      if (!((mbits >> i) & 1ull)) {
        rs[0] += exp2f(c[0]); rs[1] += exp2f(c[1]);
        rs[2] += exp2f(c[2]); rs[3] += exp2f(c[3]);
      }
      slot = (slot == 5) ? 0 : slot + 1;
      pslot = (pslot == 5) ? 0 : pslot + 1;
    }
  }

  // ---- rowsum reduction (16 t-lanes share rows) + cross-wt via red -------
  #pragma unroll
  for (int j = 0; j < 4; ++j) {
    float v = rs[j];
    v += __shfl_xor(v, 1); v += __shfl_xor(v, 2);
    v += __shfl_xor(v, 4); v += __shfl_xor(v, 8);
    rs[j] = v;
  }
  if (r16 == 0) {
    #pragma unroll
    for (int j = 0; j < 4; ++j)
      red[wt * 64 + wq * 16 + g * 4 + j] = rs[j];
  }
  __syncthreads();

  float inv_[4];
  #pragma unroll
  for (int j = 0; j < 4; ++j) {
    const int row = wq * 16 + g * 4 + j;
    inv_[j] = 1.f / (red[row] + red[64 + row]);
  }
  __syncthreads();   // red consumed before any later reuse of that region

  // ---- pass 2 prologue: K/V tiles 0..4 -----------------------------------
  stageKV(0, 0); stageKV(1, 1); stageKV(2, 2); stageKV(3, 3); stageKV(4, 4);

  f32x4 o0 = {0.f, 0.f, 0.f, 0.f}, o1 = {0.f, 0.f, 0.f, 0.f};
  // P-tile addressing (rows 64B, swizzle bits 4-5 with (row>>2)&3)
  const int parow = wq * 16 + r16;
  const int pasw  = ((parow >> 2) & 3) << 4;
  const int d0 = wt * 32 + r16;              // PV d rows (dt adds 16)
  // readback: thread -> q row tid>>3, 4 cols at (tid&7)*4 (bytes (tid&7)*8)
  const int rbq = tid >> 3;
  const int rboff = (rbq * 64 + (tid & 7) * 8) ^ (((rbq >> 2) & 3) << 4);
  float* const aT = attn + ((size_t)bh * SEQ + q0 + rbq) * SEQ + (tid & 7) * 4;

  // pass 2 (64 iters). per-wave 1 load + 1 store/iter.
  // vmcnt ladder: i=0..4 -> 4..8; i in [5,59] -> 9; i=60..63 -> 8,7,6,5.
  {
    int slot = 0, pslot = 5;
    for (int i = 0; i < 64; ++i) {
      if (i >= 5 && i <= 59)
        asm volatile("s_waitcnt vmcnt(9)\n\ts_barrier" ::: "memory");
      else if (i == 4 || i == 60)
        asm volatile("s_waitcnt vmcnt(8)\n\ts_barrier" ::: "memory");
      else if (i == 3 || i == 61)
        asm volatile("s_waitcnt vmcnt(7)\n\ts_barrier" ::: "memory");
      else if (i == 2 || i == 62)
        asm volatile("s_waitcnt vmcnt(6)\n\ts_barrier" ::: "memory");
      else if (i == 1 || i == 63)
        asm volatile("s_waitcnt vmcnt(5)\n\ts_barrier" ::: "memory");
      else
        asm volatile("s_waitcnt vmcnt(4)\n\ts_barrier" ::: "memory");
      if (i + 5 < 64) stageKV(i + 5, pslot);

      // ---- QK^T (16q x 16t, k=64)
      const char* Kt = Kbuf + (slot << 12);
      const bf16x8 kb0 = *(const bf16x8*)(Kt + krow * 128 + ((g * 16) ^ ksw));
      const bf16x8 kb1 = *(const bf16x8*)(Kt + krow * 128 + ((g * 16 + 64) ^ ksw));
      f32x4 c = {0.f, 0.f, 0.f, 0.f};
      __builtin_amdgcn_s_setprio(1);
      c = __builtin_amdgcn_mfma_f32_16x16x32_bf16(qa0, kb0, c, 0, 0, 0);
      c = __builtin_amdgcn_mfma_f32_16x16x32_bf16(qa1, kb1, c, 0, 0, 0);
      __builtin_amdgcn_s_setprio(0);

      const unsigned mk = (unsigned)((mbits >> i) & 1ull);
      #pragma unroll
      for (int j = 0; j < 4; ++j) {
        const float p = mk ? 0.f : exp2f(c[j]) * inv_[j];
        const int row = wq * 16 + g * 4 + j;
        *(unsigned short*)(Pt + ((row * 64 + tb * 2) ^ (((row >> 2) & 3) << 4))) =
            f2bf(p);
      }

      asm volatile("s_waitcnt lgkmcnt(0)\n\ts_barrier" ::: "memory");

      // ---- PV (16q x 32d window, k=32)
      const char* Vtl = Vbuf + (slot << 12);
      const bf16x8 pa = *(const bf16x8*)(Pt + parow * 64 + ((g * 16) ^ pasw));
      __builtin_amdgcn_s_setprio(1);
      {
        const int d = d0;
        const bf16x8 vb = *(const bf16x8*)(Vtl + d * 64 +
                                           ((g * 16) ^ (((d >> 2) & 3) << 4)));
        o0 = __builtin_amdgcn_mfma_f32_16x16x32_bf16(pa, vb, o0, 0, 0, 0);
      }
      {
        const int d = d0 + 16;
        const bf16x8 vb = *(const bf16x8*)(Vtl + d * 64 +
                                           ((g * 16) ^ (((d >> 2) & 3) << 4)));
        o1 = __builtin_amdgcn_mfma_f32_16x16x32_bf16(pa, vb, o1, 0, 0, 0);
      }
      __builtin_amdgcn_s_setprio(0);

      // ---- coalesced attn write: 8B LDS readback -> 1 float4 nt store
      {
        const ushort4 pv = *(const ushort4*)(Pt + rboff);
        f32x4 w;
        w[0] = bf2f(pv.x); w[1] = bf2f(pv.y);
        w[2] = bf2f(pv.z); w[3] = bf2f(pv.w);
        nt_store_f4(w, aT + (size_t)i * 32);
      }

      slot = (slot == 5) ? 0 : slot + 1;
      pslot = (pslot == 5) ? 0 : pslot + 1;
    }
  }

  // ---- O epilogue (normalized), bf16, nontemporal ------------------------
  #pragma unroll
  for (int j = 0; j < 4; ++j) {
    const int row = q0 + wq * 16 + g * 4 + j;
    const size_t base = (size_t)(b * SEQ + row) * D_MODEL + h * 64;
    __builtin_nontemporal_store(f2bf(o0[j]), &Oh[base + d0]);
    __builtin_nontemporal_store(f2bf(o1[j]), &Oh[base + d0 + 16]);
  }
}

// ---------------------------------------------------------------------------
extern "C" void kernel_launch(void* const* d_in, const int* in_sizes, int n_in,
                              void* d_out, int out_size, void* d_ws, size_t ws_size,
                              hipStream_t stream) {
  const float* v    = (const float*)d_in[0];
  const float* k    = (const float*)d_in[1];
  const float* q    = (const float*)d_in[2];
  const int*   mask = (const int*)  d_in[3];
  const float* Wq   = (const float*)d_in[4];
  const float* bq   = (const float*)d_in[5];
  const float* Wk   = (const float*)d_in[6];
  const float* bk   = (const float*)d_in[7];
  const float* Wv   = (const float*)d_in[8];
  const float* bv   = (const float*)d_in[9];
  const float* Wo   = (const float*)d_in[10];
  const float* bo   = (const float*)d_in[11];

  const size_t NTOK = (size_t)2 * SEQ;            // 4096 tokens
  const size_t TOKF = NTOK * D_MODEL;             // 4,194,304 elements
  const size_t WSZ  = (size_t)D_MODEL * D_MODEL;  // 1,048,576
  float* out  = (float*)d_out;
  float* attn = out + TOKF;

  unsigned short* qx   = (unsigned short*)d_ws;   // bf16 inputs
  unsigned short* kx   = qx + TOKF;
  unsigned short* vx   = kx + TOKF;
  unsigned short* Qbf  = vx + TOKF;               // projections
  unsigned short* Kbf  = Qbf + TOKF;
  unsigned short* Vtb  = Kbf + TOKF;
  unsigned short* Ohb  = Vtb + TOKF;              // attn O (bf16)
  unsigned short* Wqt  = Ohb + TOKF;              // transposed bf16 weights
  unsigned short* Wkt  = Wqt + WSZ;
  unsigned short* Wvt  = Wkt + WSZ;
  unsigned short* Woth = Wvt + WSZ;

  const int cvtg = (int)(TOKF / 4 / 256);         // 4096 blocks
  cvt3_bf16<<<dim3(cvtg, 3), 256, 0, stream>>>(
      (const float4*)q, (const float4*)k, (const float4*)v,
      (ushort4*)qx, (ushort4*)kx, (ushort4*)vx);
  wt_cvt4<<<dim3(16, 16, 4), 256, 0, stream>>>(Wq, Wk, Wv, Wo,
                                               Wqt, Wkt, Wvt, Woth);

  gemm_qkv<<<768, 512, 0, stream>>>(qx, kx, vx, Wqt, Wkt, Wvt,
                                    bq, bk, bv, Qbf, Kbf, Vtb);

  attn_2pass<<<1024, 512, 0, stream>>>(Qbf, Kbf, Vtb, mask, attn, Ohb);

  gemm_fin64<<<512, 512, 0, stream>>>(Ohb, Woth, bo, out);
}

// Round 15
// 226.411 us; speedup vs baseline: 1.2520x; 1.0755x over previous
//
#include <hip/hip_runtime.h>
#include <hip/hip_bf16.h>
#include <math.h>

#define D_MODEL 1024
#define SEQ     2048
#define NHEAD   16

typedef __attribute__((ext_vector_type(8))) short bf16x8;
typedef __attribute__((ext_vector_type(4))) float f32x4;
typedef const __attribute__((address_space(1))) unsigned int* gas_u32p;
typedef __attribute__((address_space(3))) unsigned int* las_u32p;

__device__ __forceinline__ void load16(const void* g, void* l) {
  __builtin_amdgcn_global_load_lds((gas_u32p)g, (las_u32p)l, 16, 0, 0);
}

__device__ __forceinline__ unsigned short f2bf(float f) {
  __hip_bfloat16 h = __float2bfloat16(f);
  return *(unsigned short*)&h;
}
__device__ __forceinline__ float bf2f(unsigned short u) {
  return __uint_as_float((unsigned)u << 16);
}
__device__ __forceinline__ void nt_store_f4(f32x4 v, float* p) {
  __builtin_nontemporal_store(v, (f32x4*)p);
}

// ---------------------------------------------------------------------------
// fp32 -> bf16 for q,k,v in one launch (blockIdx.y selects tensor)
// ---------------------------------------------------------------------------
__global__ __launch_bounds__(256) void cvt3_bf16(
    const float4* __restrict__ q, const float4* __restrict__ k,
    const float4* __restrict__ v, ushort4* __restrict__ qo,
    ushort4* __restrict__ ko, ushort4* __restrict__ vo) {
  const int i = blockIdx.x * 256 + threadIdx.x;
  const float4* in = (blockIdx.y == 0) ? q : (blockIdx.y == 1) ? k : v;
  ushort4* out = (blockIdx.y == 0) ? qo : (blockIdx.y == 1) ? ko : vo;
  const float4 f = in[i];
  ushort4 u;
  u.x = f2bf(f.x); u.y = f2bf(f.y); u.z = f2bf(f.z); u.w = f2bf(f.w);
  out[i] = u;
}

// ---------------------------------------------------------------------------
// 4 x (W [1024 k][1024 n] fp32 -> Wt bf16 [n][k]), blockIdx.z selects
// ---------------------------------------------------------------------------
__global__ __launch_bounds__(256) void wt_cvt4(
    const float* __restrict__ W0, const float* __restrict__ W1,
    const float* __restrict__ W2, const float* __restrict__ W3,
    unsigned short* __restrict__ O0, unsigned short* __restrict__ O1,
    unsigned short* __restrict__ O2, unsigned short* __restrict__ O3) {
  __shared__ float t[64][65];
  const int z = blockIdx.z;
  const float* W = (z == 0) ? W0 : (z == 1) ? W1 : (z == 2) ? W2 : W3;
  unsigned short* Wh = (z == 0) ? O0 : (z == 1) ? O1 : (z == 2) ? O2 : O3;
  const int tid = threadIdx.x;
  const int k0 = blockIdx.y * 64, n0 = blockIdx.x * 64;
  #pragma unroll
  for (int it = 0; it < 4; ++it) {
    const int r = it * 16 + (tid >> 4), c4 = (tid & 15) * 4;
    const float4 f = *(const float4*)&W[(size_t)(k0 + r) * D_MODEL + n0 + c4];
    t[r][c4 + 0] = f.x; t[r][c4 + 1] = f.y;
    t[r][c4 + 2] = f.z; t[r][c4 + 3] = f.w;
  }
  __syncthreads();
  #pragma unroll
  for (int it = 0; it < 4; ++it) {
    const int n = it * 16 + (tid >> 4), k4 = (tid & 15) * 4;
    ushort4 uh;
    uh.x = f2bf(t[k4 + 0][n]); uh.y = f2bf(t[k4 + 1][n]);
    uh.z = f2bf(t[k4 + 2][n]); uh.w = f2bf(t[k4 + 3][n]);
    *(ushort4*)&Wh[(size_t)(n0 + n) * D_MODEL + k0 + k4] = uh;
  }
}

// ---------------------------------------------------------------------------
// Fused Q/K/V projections. 128x128 tile, BK=64, grid 768 (validated r7-r14).
// Q pre-scaled by 0.125*log2(e).
// ---------------------------------------------------------------------------
__global__ __launch_bounds__(512, 4) void gemm_qkv(
    const unsigned short* __restrict__ qx, const unsigned short* __restrict__ kx,
    const unsigned short* __restrict__ vx,
    const unsigned short* __restrict__ Wqt, const unsigned short* __restrict__ Wkt,
    const unsigned short* __restrict__ Wvt,
    const float* __restrict__ bq, const float* __restrict__ bk,
    const float* __restrict__ bv,
    unsigned short* __restrict__ Qo, unsigned short* __restrict__ Ko,
    unsigned short* __restrict__ Vto) {
  __shared__ char lds[65536];
  const int tid = threadIdx.x;
  const int lane = tid & 63, wid = tid >> 6;
  const int r16 = lane & 15, g = lane >> 4;
  const int bid = blockIdx.x;
  const int orig = (bid & 7) * 96 + (bid >> 3);
  const int which = orig >> 8;
  const int sub = orig & 255;
  const int bm = sub >> 3, bn = sub & 7;
  const int row0 = bm * 128, col0 = bn * 128;
  const int wm = wid >> 2, wn = wid & 3;

  const unsigned short* A = (which == 0) ? qx : (which == 1) ? kx : vx;
  const unsigned short* W = (which == 0) ? Wqt : (which == 1) ? Wkt : Wvt;
  const float* bias = (which == 0) ? bq : (which == 1) ? bk : bv;

  const unsigned short* Ag = A + (size_t)row0 * D_MODEL;
  const unsigned short* Bg = W + (size_t)col0 * D_MODEL;

  auto stage = [&](int buf, int k0) {
    char* base = lds + buf * 32768;
    #pragma unroll
    for (int c = 0; c < 2; ++c) {
      const int idx = c * 512 + tid;
      const int r = idx >> 3, ch = idx & 7;
      const size_t off = (size_t)r * D_MODEL + k0 + ((ch ^ (r & 7)) << 3);
      load16(Ag + off, base + idx * 16);
      load16(Bg + off, base + 16384 + idx * 16);
    }
  };

  stage(0, 0);
  f32x4 acc[4][2] = {};

  for (int s = 0; s < 16; ++s) {
    __syncthreads();
    if (s < 15) stage((s + 1) & 1, (s + 1) * 64);
    const char* base = lds + (s & 1) * 32768;
    #pragma unroll
    for (int kk = 0; kk < 2; ++kk) {
      bf16x8 a[4], b[2];
      #pragma unroll
      for (int mi = 0; mi < 4; ++mi) {
        const int r = wm * 64 + mi * 16 + r16;
        a[mi] = *(const bf16x8*)(base + r * 128 + (((g + kk * 4) ^ (r & 7)) << 4));
      }
      #pragma unroll
      for (int ni = 0; ni < 2; ++ni) {
        const int r = wn * 32 + ni * 16 + r16;
        b[ni] = *(const bf16x8*)(base + 16384 + r * 128 +
                                 (((g + kk * 4) ^ (r & 7)) << 4));
      }
      #pragma unroll
      for (int mi = 0; mi < 4; ++mi)
        #pragma unroll
        for (int ni = 0; ni < 2; ++ni)
          acc[mi][ni] = __builtin_amdgcn_mfma_f32_16x16x32_bf16(
              a[mi], b[ni], acc[mi][ni], 0, 0, 0);
    }
  }

  if (which < 2) {
    unsigned short* C = (which == 0) ? Qo : Ko;
    const float scale = (which == 0) ? 0.1803368802f : 1.0f;
    #pragma unroll
    for (int mi = 0; mi < 4; ++mi)
      #pragma unroll
      for (int ni = 0; ni < 2; ++ni) {
        const int col = col0 + wn * 32 + ni * 16 + r16;
        const float bb = bias[col];
        const int rowb = row0 + wm * 64 + mi * 16 + g * 4;
        #pragma unroll
        for (int j = 0; j < 4; ++j)
          C[(size_t)(rowb + j) * D_MODEL + col] =
              f2bf((acc[mi][ni][j] + bb) * scale);
      }
  } else {
    #pragma unroll
    for (int mi = 0; mi < 4; ++mi)
      #pragma unroll
      for (int ni = 0; ni < 2; ++ni) {
        const int col = col0 + wn * 32 + ni * 16 + r16;
        const int hh = col >> 6, dd = col & 63;
        const float bb = bias[col];
        const int rowb = row0 + wm * 64 + mi * 16 + g * 4;
        const int b_ = rowb >> 11, tt = rowb & 2047;
        ushort4 u;
        u.x = f2bf(acc[mi][ni][0] + bb);
        u.y = f2bf(acc[mi][ni][1] + bb);
        u.z = f2bf(acc[mi][ni][2] + bb);
        u.w = f2bf(acc[mi][ni][3] + bb);
        *(ushort4*)&Vto[((size_t)((b_ * NHEAD + hh) * 64 + dd)) * SEQ + tt] = u;
      }
  }
}

// ---------------------------------------------------------------------------
// Final GEMM: out = Oh @ Wh + bias, fp32. 64x128 tile, BK=64, grid 512.
// launch_bounds (512,6): 49 KB LDS now allows 3 blocks/CU.
// ---------------------------------------------------------------------------
__global__ __launch_bounds__(512, 6) void gemm_fin64(
    const unsigned short* __restrict__ A, const unsigned short* __restrict__ B,
    const float* __restrict__ bias, float* __restrict__ O) {
  __shared__ char lds[49152];
  const int tid = threadIdx.x;
  const int lane = tid & 63, wid = tid >> 6;
  const int r16 = lane & 15, g = lane >> 4;
  const int bid = blockIdx.x;
  const int orig = (bid & 7) * 64 + (bid >> 3);
  const int bm = orig >> 3, bn = orig & 7;
  const int row0 = bm * 64, col0 = bn * 128;
  const int wm = wid >> 2, wn = wid & 3;

  const unsigned short* Ag = A + (size_t)row0 * D_MODEL;
  const unsigned short* Bg = B + (size_t)col0 * D_MODEL;

  auto stage = [&](int buf, int k0) {
    char* base = lds + buf * 24576;
    {
      const int r = tid >> 3, ch = tid & 7;
      load16(Ag + (size_t)r * D_MODEL + k0 + ((ch ^ (r & 7)) << 3),
             base + tid * 16);
    }
    #pragma unroll
    for (int c = 0; c < 2; ++c) {
      const int idx = c * 512 + tid;
      const int r = idx >> 3, ch = idx & 7;
      load16(Bg + (size_t)r * D_MODEL + k0 + ((ch ^ (r & 7)) << 3),
             base + 8192 + idx * 16);
    }
  };

  stage(0, 0);
  f32x4 acc[2][2] = {};

  for (int s = 0; s < 16; ++s) {
    __syncthreads();
    if (s < 15) stage((s + 1) & 1, (s + 1) * 64);
    const char* base = lds + (s & 1) * 24576;
    #pragma unroll
    for (int kk = 0; kk < 2; ++kk) {
      bf16x8 a[2], b[2];
      #pragma unroll
      for (int mi = 0; mi < 2; ++mi) {
        const int r = wm * 32 + mi * 16 + r16;
        a[mi] = *(const bf16x8*)(base + r * 128 + (((g + kk * 4) ^ (r & 7)) << 4));
      }
      #pragma unroll
      for (int ni = 0; ni < 2; ++ni) {
        const int r = wn * 32 + ni * 16 + r16;
        b[ni] = *(const bf16x8*)(base + 8192 + r * 128 +
                                 (((g + kk * 4) ^ (r & 7)) << 4));
      }
      #pragma unroll
      for (int mi = 0; mi < 2; ++mi)
        #pragma unroll
        for (int ni = 0; ni < 2; ++ni)
          acc[mi][ni] = __builtin_amdgcn_mfma_f32_16x16x32_bf16(
              a[mi], b[ni], acc[mi][ni], 0, 0, 0);
    }
  }

  #pragma unroll
  for (int mi = 0; mi < 2; ++mi)
    #pragma unroll
    for (int ni = 0; ni < 2; ++ni) {
      const int col = col0 + wn * 32 + ni * 16 + r16;
      const float bb = bias[col];
      const int rowb = row0 + wm * 32 + mi * 16 + g * 4;
      #pragma unroll
      for (int j = 0; j < 4; ++j)
        __builtin_nontemporal_store(
            acc[mi][ni][j] + bb,
            &O[(size_t)(rowb + j) * D_MODEL + col]);
    }
}

// ---------------------------------------------------------------------------
// Two-pass MFMA attention, QB=64, 32-t tiles, ring-4 K/V, 36.5 KB LDS ->
// 4 blocks/CU (32 waves, full occupancy). Waves: wq(0..3) x wt(0..1).
// Waves 0-3 stage K, 4-7 stage V (1 vm-load/wave/iter). Prefetch depth 3.
// vmcnt ladders: pass1 2..2,1,0; pass2 2,3,4,5x[3..61],4,3.
// ---------------------------------------------------------------------------
__global__ __launch_bounds__(512, 8) void attn_2pass(
    const unsigned short* __restrict__ Qb,   // bf16, pre-scaled 0.125*log2e
    const unsigned short* __restrict__ Kb,   // bf16 [4096][1024]
    const unsigned short* __restrict__ Vt,   // bf16 [32*64][2048]
    const int* __restrict__ mask,            // [2][2048]
    float* __restrict__ attn,                // [32][2048][2048]
    unsigned short* __restrict__ Oh) {       // bf16 [4096][1024]
  __shared__ char lds[37376];
  char* const Kbuf = lds;                    // 4 x 4096: K tiles [32 t][128B]
  char* const Vbuf = lds + 16384;            // 4 x 4096: V tiles [64 d][64B]
  char* const Pt   = lds + 32768;            // 4096: P tile [64 q][64B]
  float* const red = (float*)(lds + 36864);  // [2 wt][64 q]

  const int tid  = threadIdx.x;
  const int lane = tid & 63;
  const int wid  = tid >> 6;
  const int r16  = lane & 15;
  const int g    = lane >> 4;
  const int wq   = wid >> 1;                 // q-quarter (16 rows)
  const int wt   = wid & 1;                  // t half (QK) / d half (PV)

  const int bid  = blockIdx.x;
  const int orig = (bid & 7) * 128 + (bid >> 3);   // XCD swizzle (1024%8==0)
  const int bh   = orig >> 5;
  const int qblk = orig & 31;
  const int b    = bh >> 4, h = bh & 15;
  const int q0   = qblk * 64;

  const unsigned short* Kg0 = Kb + (size_t)(b * SEQ) * D_MODEL + h * 64;
  const unsigned short* Qg0 = Qb + (size_t)(b * SEQ + q0) * D_MODEL + h * 64;
  const unsigned short* Vg0 = Vt + (size_t)(bh * 64) * SEQ;
  const int* mrow = mask + b * SEQ;

  // staging: waves 0-3 (tid<256) stage K tiles, waves 4-7 stage V tiles.
  const int t8 = tid & 255;
  const int ks_row = t8 >> 3, ks_ch = t8 & 7;      // K: 32 rows x 8 chunks
  const int vs_row = t8 >> 2, vs_ch = t8 & 3;      // V: 64 rows x 4 chunks
  auto stageK = [&](int t, int slot) {
    load16((const char*)(Kg0 + (size_t)(t * 32 + ks_row) * D_MODEL) +
               ((ks_ch ^ (ks_row & 7)) << 4),
           Kbuf + (slot << 12) + t8 * 16);
  };
  auto stageV = [&](int t, int slot) {
    load16((const char*)(Vg0 + (size_t)vs_row * SEQ + t * 32) +
               ((vs_ch ^ ((vs_row >> 2) & 3)) << 4),
           Vbuf + (slot << 12) + t8 * 16);
  };
  auto stageKV = [&](int t, int slot) {
    if (tid < 256) stageK(t, slot); else stageV(t, slot);
  };

  // per-lane mask bits for t = i*32 + wt*16 + r16, i in [0,64)
  const int tb = wt * 16 + r16;
  unsigned long long mbits = 0;
  #pragma unroll 8
  for (int i = 0; i < 64; ++i)
    mbits |= (unsigned long long)(mrow[i * 32 + tb] ? 1 : 0) << i;
  asm volatile("s_waitcnt vmcnt(0)" ::: "memory");

  // ---- pass 1 prologue: Q into Vbuf (8K), K tiles 0..2 -------------------
  load16((const char*)(Qg0 + (size_t)(tid >> 3) * D_MODEL) +
             (((tid & 7) ^ ((tid >> 3) & 7)) << 4),
         Vbuf + tid * 16);
  if (tid < 256) { stageK(0, 0); stageK(1, 1); stageK(2, 2); }
  asm volatile("s_waitcnt vmcnt(0)\n\ts_barrier" ::: "memory");

  bf16x8 qa0, qa1;
  {
    const int row = wq * 16 + r16;
    const int sw = (row & 7) << 4;
    qa0 = *(const bf16x8*)(Vbuf + row * 128 + ((g * 16) ^ sw));
    qa1 = *(const bf16x8*)(Vbuf + row * 128 + ((g * 16 + 64) ^ sw));
  }

  const int krow = wt * 16 + r16;            // t-row in K tile [0,32)
  const int ksw  = (krow & 7) << 4;

  // ---- pass 1: rowsums (64 iters, ring-4, depth-3) -----------------------
  float rs[4] = {};
  for (int i = 0; i < 64; ++i) {
    if (i <= 61)
      asm volatile("s_waitcnt vmcnt(2)\n\ts_barrier" ::: "memory");
    else if (i == 62)
      asm volatile("s_waitcnt vmcnt(1)\n\ts_barrier" ::: "memory");
    else
      asm volatile("s_waitcnt vmcnt(0)\n\ts_barrier" ::: "memory");
    if (i + 3 < 64 && tid < 256) stageK(i + 3, (i + 3) & 3);
    const char* Kt = Kbuf + ((i & 3) << 12);
    const bf16x8 kb0 = *(const bf16x8*)(Kt + krow * 128 + ((g * 16) ^ ksw));
    const bf16x8 kb1 = *(const bf16x8*)(Kt + krow * 128 + ((g * 16 + 64) ^ ksw));
    f32x4 c = {0.f, 0.f, 0.f, 0.f};
    __builtin_amdgcn_s_setprio(1);
    c = __builtin_amdgcn_mfma_f32_16x16x32_bf16(qa0, kb0, c, 0, 0, 0);
    c = __builtin_amdgcn_mfma_f32_16x16x32_bf16(qa1, kb1, c, 0, 0, 0);
    __builtin_amdgcn_s_setprio(0);
    if (!((mbits >> i) & 1ull)) {
      rs[0] += exp2f(c[0]); rs[1] += exp2f(c[1]);
      rs[2] += exp2f(c[2]); rs[3] += exp2f(c[3]);
    }
  }

  // ---- rowsum reduction (16 t-lanes share rows) + cross-wt via red -------
  #pragma unroll
  for (int j = 0; j < 4; ++j) {
    float v = rs[j];
    v += __shfl_xor(v, 1); v += __shfl_xor(v, 2);
    v += __shfl_xor(v, 4); v += __shfl_xor(v, 8);
    rs[j] = v;
  }
  if (r16 == 0) {
    #pragma unroll
    for (int j = 0; j < 4; ++j)
      red[wt * 64 + wq * 16 + g * 4 + j] = rs[j];
  }
  __syncthreads();

  float inv_[4];
  #pragma unroll
  for (int j = 0; j < 4; ++j) {
    const int row = wq * 16 + g * 4 + j;
    inv_[j] = 1.f / (red[row] + red[64 + row]);
  }
  __syncthreads();

  // ---- pass 2 prologue: K/V tiles 0..2 -----------------------------------
  stageKV(0, 0); stageKV(1, 1); stageKV(2, 2);

  f32x4 o0 = {0.f, 0.f, 0.f, 0.f}, o1 = {0.f, 0.f, 0.f, 0.f};
  const int parow = wq * 16 + r16;
  const int pasw  = ((parow >> 2) & 3) << 4;
  const int d0 = wt * 32 + r16;
  const int rbq = tid >> 3;
  const int rboff = (rbq * 64 + (tid & 7) * 8) ^ (((rbq >> 2) & 3) << 4);
  float* const aT = attn + ((size_t)bh * SEQ + q0 + rbq) * SEQ + (tid & 7) * 4;

  // pass 2 (64 iters, ring-4, depth-3; 1 load + 1 store/wave/iter).
  for (int i = 0; i < 64; ++i) {
    if (i >= 3 && i <= 61)
      asm volatile("s_waitcnt vmcnt(5)\n\ts_barrier" ::: "memory");
    else if (i == 2 || i == 62)
      asm volatile("s_waitcnt vmcnt(4)\n\ts_barrier" ::: "memory");
    else if (i == 1 || i == 63)
      asm volatile("s_waitcnt vmcnt(3)\n\ts_barrier" ::: "memory");
    else
      asm volatile("s_waitcnt vmcnt(2)\n\ts_barrier" ::: "memory");
    if (i + 3 < 64) stageKV(i + 3, (i + 3) & 3);

    // ---- QK^T (16q x 16t, k=64)
    const char* Kt = Kbuf + ((i & 3) << 12);
    const bf16x8 kb0 = *(const bf16x8*)(Kt + krow * 128 + ((g * 16) ^ ksw));
    const bf16x8 kb1 = *(const bf16x8*)(Kt + krow * 128 + ((g * 16 + 64) ^ ksw));
    f32x4 c = {0.f, 0.f, 0.f, 0.f};
    __builtin_amdgcn_s_setprio(1);
    c = __builtin_amdgcn_mfma_f32_16x16x32_bf16(qa0, kb0, c, 0, 0, 0);
    c = __builtin_amdgcn_mfma_f32_16x16x32_bf16(qa1, kb1, c, 0, 0, 0);
    __builtin_amdgcn_s_setprio(0);

    const unsigned mk = (unsigned)((mbits >> i) & 1ull);
    #pragma unroll
    for (int j = 0; j < 4; ++j) {
      const float p = mk ? 0.f : exp2f(c[j]) * inv_[j];
      const int row = wq * 16 + g * 4 + j;
      *(unsigned short*)(Pt + ((row * 64 + tb * 2) ^ (((row >> 2) & 3) << 4))) =
          f2bf(p);
    }

    asm volatile("s_waitcnt lgkmcnt(0)\n\ts_barrier" ::: "memory");

    // ---- PV (16q x 32d window, k=32)
    const char* Vtl = Vbuf + ((i & 3) << 12);
    const bf16x8 pa = *(const bf16x8*)(Pt + parow * 64 + ((g * 16) ^ pasw));
    __builtin_amdgcn_s_setprio(1);
    {
      const int d = d0;
      const bf16x8 vb = *(const bf16x8*)(Vtl + d * 64 +
                                         ((g * 16) ^ (((d >> 2) & 3) << 4)));
      o0 = __builtin_amdgcn_mfma_f32_16x16x32_bf16(pa, vb, o0, 0, 0, 0);
    }
    {
      const int d = d0 + 16;
      const bf16x8 vb = *(const bf16x8*)(Vtl + d * 64 +
                                         ((g * 16) ^ (((d >> 2) & 3) << 4)));
      o1 = __builtin_amdgcn_mfma_f32_16x16x32_bf16(pa, vb, o1, 0, 0, 0);
    }
    __builtin_amdgcn_s_setprio(0);

    // ---- coalesced attn write: 8B LDS readback -> 1 float4 nt store
    {
      const ushort4 pv = *(const ushort4*)(Pt + rboff);
      f32x4 w;
      w[0] = bf2f(pv.x); w[1] = bf2f(pv.y);
      w[2] = bf2f(pv.z); w[3] = bf2f(pv.w);
      nt_store_f4(w, aT + (size_t)i * 32);
    }
  }

  // ---- O epilogue (normalized), bf16, nontemporal ------------------------
  #pragma unroll
  for (int j = 0; j < 4; ++j) {
    const int row = q0 + wq * 16 + g * 4 + j;
    const size_t base = (size_t)(b * SEQ + row) * D_MODEL + h * 64;
    __builtin_nontemporal_store(f2bf(o0[j]), &Oh[base + d0]);
    __builtin_nontemporal_store(f2bf(o1[j]), &Oh[base + d0 + 16]);
  }
}

// ---------------------------------------------------------------------------
extern "C" void kernel_launch(void* const* d_in, const int* in_sizes, int n_in,
                              void* d_out, int out_size, void* d_ws, size_t ws_size,
                              hipStream_t stream) {
  const float* v    = (const float*)d_in[0];
  const float* k    = (const float*)d_in[1];
  const float* q    = (const float*)d_in[2];
  const int*   mask = (const int*)  d_in[3];
  const float* Wq   = (const float*)d_in[4];
  const float* bq   = (const float*)d_in[5];
  const float* Wk   = (const float*)d_in[6];
  const float* bk   = (const float*)d_in[7];
  const float* Wv   = (const float*)d_in[8];
  const float* bv   = (const float*)d_in[9];
  const float* Wo   = (const float*)d_in[10];
  const float* bo   = (const float*)d_in[11];

  const size_t NTOK = (size_t)2 * SEQ;            // 4096 tokens
  const size_t TOKF = NTOK * D_MODEL;             // 4,194,304 elements
  const size_t WSZ  = (size_t)D_MODEL * D_MODEL;  // 1,048,576
  float* out  = (float*)d_out;
  float* attn = out + TOKF;

  unsigned short* qx   = (unsigned short*)d_ws;   // bf16 inputs
  unsigned short* kx   = qx + TOKF;
  unsigned short* vx   = kx + TOKF;
  unsigned short* Qbf  = vx + TOKF;               // projections
  unsigned short* Kbf  = Qbf + TOKF;
  unsigned short* Vtb  = Kbf + TOKF;
  unsigned short* Ohb  = Vtb + TOKF;              // attn O (bf16)
  unsigned short* Wqt  = Ohb + TOKF;              // transposed bf16 weights
  unsigned short* Wkt  = Wqt + WSZ;
  unsigned short* Wvt  = Wkt + WSZ;
  unsigned short* Woth = Wvt + WSZ;

  const int cvtg = (int)(TOKF / 4 / 256);         // 4096 blocks
  cvt3_bf16<<<dim3(cvtg, 3), 256, 0, stream>>>(
      (const float4*)q, (const float4*)k, (const float4*)v,
      (ushort4*)qx, (ushort4*)kx, (ushort4*)vx);
  wt_cvt4<<<dim3(16, 16, 4), 256, 0, stream>>>(Wq, Wk, Wv, Wo,
                                               Wqt, Wkt, Wvt, Woth);

  gemm_qkv<<<768, 512, 0, stream>>>(qx, kx, vx, Wqt, Wkt, Wvt,
                                    bq, bk, bv, Qbf, Kbf, Vtb);

  attn_2pass<<<1024, 512, 0, stream>>>(Qbf, Kbf, Vtb, mask, attn, Ohb);

  gemm_fin64<<<512, 512, 0, stream>>>(Ohb, Woth, bo, out);
}